// Round 1
// baseline (380.957 us; speedup 1.0000x reference)
//
#include <hip/hip_runtime.h>

#define DN 96
#define TILE 64

// ---------------------------------------------------------------------------
// edge_index may arrive as int32 (per harness doc) or int64 (per reference).
// Detect at runtime: if stored int64, every high 32-bit word is 0 (indices
// < 50000). Probability of 1024 random int32 indices all being 0 is ~0.
// ---------------------------------------------------------------------------
__device__ __forceinline__ int edge_at(const void* ei, long long idx, int use64) {
    if (use64) return (int)((const long long*)ei)[idx];
    return ((const int*)ei)[idx];
}

__global__ void detect_i64(const unsigned int* w, int* flagp) {
    __shared__ int ok;
    if (threadIdx.x == 0) ok = 1;
    __syncthreads();
    for (int i = threadIdx.x; i < 1024; i += blockDim.x)
        if (w[2 * i + 1] != 0u) ok = 0;
    __syncthreads();
    if (threadIdx.x == 0) flagp[0] = ok;
}

// ---------------------------------------------------------------------------
// CSR build: histogram of dst -> exclusive scan -> scatter src ids
// ---------------------------------------------------------------------------
__global__ void count_deg(const void* ei, long long E, const int* flagp, int* cnt) {
    int use64 = flagp[0];
    long long e = (long long)blockIdx.x * blockDim.x + threadIdx.x;
    if (e < E) {
        int dst = edge_at(ei, E + e, use64);
        atomicAdd(&cnt[dst], 1);
    }
}

// single block, 1024 threads; data is cnt on input, exclusive-scan (rowptr)
// on output (in place, aliasing intended); cursor gets a copy.
__global__ void scan_excl(int* data, int* cursor, int n) {
    __shared__ int swsum[16];
    int tid = threadIdx.x;
    int lane = tid & 63, wid = tid >> 6;
    int carry = 0;
    for (int base = 0; base < n; base += 1024) {
        int i = base + tid;
        int v = (i < n) ? data[i] : 0;
        int sv = v;
#pragma unroll
        for (int off = 1; off < 64; off <<= 1) {
            int t = __shfl_up(sv, off, 64);
            if (lane >= off) sv += t;
        }
        __syncthreads();   // protect swsum reads from previous chunk
        if (lane == 63) swsum[wid] = sv;
        __syncthreads();
        if (tid < 16) {
            int wv = swsum[tid];
#pragma unroll
            for (int off = 1; off < 16; off <<= 1) {
                int t = __shfl_up(wv, off, 16);
                if (tid >= off) wv += t;
            }
            swsum[tid] = wv;
        }
        __syncthreads();
        int woff = (wid > 0) ? swsum[wid - 1] : 0;
        int excl = carry + woff + sv - v;
        if (i < n) { data[i] = excl; cursor[i] = excl; }
        carry += swsum[15];
    }
    if (tid == 0) data[n] = carry;
}

__global__ void scatter_edges(const void* ei, long long E, const int* flagp,
                              int* cursor, int* srcs) {
    int use64 = flagp[0];
    long long e = (long long)blockIdx.x * blockDim.x + threadIdx.x;
    if (e < E) {
        int dst = edge_at(ei, E + e, use64);
        int s   = edge_at(ei, e, use64);
        int pos = atomicAdd(&cursor[dst], 1);
        srcs[pos] = s;
    }
}

// ---------------------------------------------------------------------------
// CSR aggregation: thread = (node, float4 chunk). 24 chunks cover D=96.
// Optionally divides by max(deg,1) (conv2's neighbor_norm).
// ---------------------------------------------------------------------------
__global__ void aggregate(const float* __restrict__ in, float* __restrict__ out,
                          const int* __restrict__ rowptr, const int* __restrict__ srcs,
                          int n, int normalize) {
    int t = blockIdx.x * blockDim.x + threadIdx.x;
    if (t >= n * 24) return;
    int node = t / 24, c = t % 24;
    int beg = rowptr[node], end = rowptr[node + 1];
    float ax = 0.f, ay = 0.f, az = 0.f, aw = 0.f;
    for (int i = beg; i < end; ++i) {
        int s = srcs[i];
        const float4 v = *(const float4*)(in + (size_t)s * DN + c * 4);
        ax += v.x; ay += v.y; az += v.z; aw += v.w;
    }
    if (normalize) {
        float inv = 1.0f / fmaxf((float)(end - beg), 1.0f);
        ax *= inv; ay *= inv; az *= inv; aw *= inv;
    }
    float4 r = make_float4(ax, ay, az, aw);
    *(float4*)(out + (size_t)node * DN + c * 4) = r;
}

// ---------------------------------------------------------------------------
// out[n, j] = sum_k A[n,k] Wa[k,j] + sum_k B[n,k] Wb[k,j] + bias[j]
// wtrans=0: W row-major [96][96] (conv weights)
// wtrans=1: W is lin_w with layout [j][192] (row stride 192), chunk offset via
//           pointer (+0 / +96): Ws[k][j] = W[j*192 + k]
// Block: 256 threads, 64 rows x 96 cols; thread = 4 rows x 6 cols.
// ---------------------------------------------------------------------------
__global__ __launch_bounds__(256) void gemm2(
        const float* __restrict__ inA, const float* __restrict__ inB,
        const float* __restrict__ Wa, const float* __restrict__ Wb,
        const float* __restrict__ bias, float* __restrict__ out,
        int n, int wtrans, int dorelu) {
    __shared__ float As[DN][TILE + 4];   // [96][68], transposed A tile
    __shared__ float Ws[DN][DN + 1];     // [96][97]
    int tid = threadIdx.x;
    int row0 = blockIdx.x * TILE;
    int tc = tid & 15, tr = tid >> 4;

    float acc[4][6];
#pragma unroll
    for (int r = 0; r < 4; ++r)
#pragma unroll
        for (int c = 0; c < 6; ++c) acc[r][c] = 0.f;

    for (int ch = 0; ch < 2; ++ch) {
        const float* in = ch ? inB : inA;
        const float* W  = ch ? Wb  : Wa;
        if (!wtrans) {
            for (int i = tid; i < DN * 24; i += 256) {
                int k = i / 24, q = i % 24;
                const float4 v = *(const float4*)(W + (size_t)k * DN + q * 4);
                Ws[k][q * 4 + 0] = v.x; Ws[k][q * 4 + 1] = v.y;
                Ws[k][q * 4 + 2] = v.z; Ws[k][q * 4 + 3] = v.w;
            }
        } else {
            for (int i = tid; i < DN * 24; i += 256) {
                int j = i % DN, q = i / DN;
                const float4 v = *(const float4*)(W + (size_t)j * 192 + q * 4);
                Ws[q * 4 + 0][j] = v.x; Ws[q * 4 + 1][j] = v.y;
                Ws[q * 4 + 2][j] = v.z; Ws[q * 4 + 3][j] = v.w;
            }
        }
        for (int i = tid; i < TILE * 24; i += 256) {
            int q = i >> 6, r = i & 63;   // lanes walk rows -> conflict-free LDS writes
            float4 v = make_float4(0.f, 0.f, 0.f, 0.f);
            if (row0 + r < n) v = *(const float4*)(in + (size_t)(row0 + r) * DN + q * 4);
            As[q * 4 + 0][r] = v.x; As[q * 4 + 1][r] = v.y;
            As[q * 4 + 2][r] = v.z; As[q * 4 + 3][r] = v.w;
        }
        __syncthreads();
#pragma unroll 4
        for (int k = 0; k < DN; ++k) {
            const float4 a = *(const float4*)&As[k][tr * 4];
            float w0 = Ws[k][tc +  0], w1 = Ws[k][tc + 16], w2 = Ws[k][tc + 32];
            float w3 = Ws[k][tc + 48], w4 = Ws[k][tc + 64], w5 = Ws[k][tc + 80];
            acc[0][0] += a.x * w0; acc[0][1] += a.x * w1; acc[0][2] += a.x * w2;
            acc[0][3] += a.x * w3; acc[0][4] += a.x * w4; acc[0][5] += a.x * w5;
            acc[1][0] += a.y * w0; acc[1][1] += a.y * w1; acc[1][2] += a.y * w2;
            acc[1][3] += a.y * w3; acc[1][4] += a.y * w4; acc[1][5] += a.y * w5;
            acc[2][0] += a.z * w0; acc[2][1] += a.z * w1; acc[2][2] += a.z * w2;
            acc[2][3] += a.z * w3; acc[2][4] += a.z * w4; acc[2][5] += a.z * w5;
            acc[3][0] += a.w * w0; acc[3][1] += a.w * w1; acc[3][2] += a.w * w2;
            acc[3][3] += a.w * w3; acc[3][4] += a.w * w4; acc[3][5] += a.w * w5;
        }
        __syncthreads();
    }

    float b[6];
#pragma unroll
    for (int c = 0; c < 6; ++c) b[c] = bias[tc + 16 * c];
#pragma unroll
    for (int rr = 0; rr < 4; ++rr) {
        int row = row0 + tr * 4 + rr;
        if (row < n) {
#pragma unroll
            for (int c = 0; c < 6; ++c) {
                float v = acc[rr][c] + b[c];
                if (dorelu) v = fmaxf(v, 0.f);
                out[(size_t)row * DN + tc + 16 * c] = v;
            }
        }
    }
}

// ---------------------------------------------------------------------------
extern "C" void kernel_launch(void* const* d_in, const int* in_sizes, int n_in,
                              void* d_out, int out_size, void* d_ws, size_t ws_size,
                              hipStream_t stream) {
    const float* x   = (const float*)d_in[0];
    const void*  ei  = d_in[1];
    const float* W1r = (const float*)d_in[2];
    const float* W1n = (const float*)d_in[3];
    const float* b1  = (const float*)d_in[4];
    const float* W2r = (const float*)d_in[5];
    const float* W2n = (const float*)d_in[6];
    const float* b2  = (const float*)d_in[7];
    const float* lw  = (const float*)d_in[8];
    const float* lb  = (const float*)d_in[9];
    float* out = (float*)d_out;

    const int N = in_sizes[0] / DN;         // 50000
    const long long E = in_sizes[1] / 2;    // 800000

    float* agg = (float*)d_ws;
    float* h1  = agg + (size_t)N * DN;
    float* h2  = h1 + (size_t)N * DN;
    int* rowptr = (int*)(h2 + (size_t)N * DN);   // N+1 (also the histogram)
    int* cursor = rowptr + (N + 1);              // N
    int* srcs   = cursor + N;                    // E
    int* flagp  = srcs + E;                      // 1

    hipMemsetAsync(rowptr, 0, (N + 1) * sizeof(int), stream);
    detect_i64<<<1, 256, 0, stream>>>((const unsigned int*)ei, flagp);

    int eb = (int)((E + 255) / 256);
    count_deg<<<eb, 256, 0, stream>>>(ei, E, flagp, rowptr);
    scan_excl<<<1, 1024, 0, stream>>>(rowptr, cursor, N);
    scatter_edges<<<eb, 256, 0, stream>>>(ei, E, flagp, cursor, srcs);

    int ab = (N * 24 + 255) / 256;
    int gb = (N + TILE - 1) / TILE;

    // conv1: h1 = x@W1r + agg(x)@W1n + b1
    aggregate<<<ab, 256, 0, stream>>>(x, agg, rowptr, srcs, N, 0);
    gemm2<<<gb, 256, 0, stream>>>(x, agg, W1r, W1n, b1, h1, N, 0, 0);
    // conv2: h2 = h1@W2r + (agg(h1)/deg)@W2n + b2
    aggregate<<<ab, 256, 0, stream>>>(h1, agg, rowptr, srcs, N, 1);
    gemm2<<<gb, 256, 0, stream>>>(h1, agg, W2r, W2n, b2, h2, N, 0, 0);
    // out = relu([h1|h2] @ lin_w.T + lin_b)
    gemm2<<<gb, 256, 0, stream>>>(h1, h2, lw, lw + DN, lb, out, N, 1, 1);
}

// Round 2
// 252.163 us; speedup vs baseline: 1.5108x; 1.5108x over previous
//
#include <hip/hip_runtime.h>

#define DN 96
#define TILE 64
#define NCHUNK 256

// ---------------------------------------------------------------------------
// helpers
// ---------------------------------------------------------------------------
__device__ __forceinline__ int edge_at(const void* ei, long long idx, int use64) {
    if (use64) return (int)((const long long*)ei)[idx];
    return ((const int*)ei)[idx];
}

__device__ __forceinline__ unsigned short f2bf(float f) {
    unsigned int u = __float_as_uint(f);
    return (unsigned short)((u + 0x7fffu + ((u >> 16) & 1u)) >> 16);  // RNE
}

__global__ void detect_i64(const unsigned int* w, int* flagp) {
    __shared__ int ok;
    if (threadIdx.x == 0) ok = 1;
    __syncthreads();
    for (int i = threadIdx.x; i < 1024; i += blockDim.x)
        if (w[2 * i + 1] != 0u) ok = 0;
    __syncthreads();
    if (threadIdx.x == 0) flagp[0] = ok;
}

// x (fp32) -> packed bf16 pairs (uint): low ushort = even elem
__global__ void to_bf16(const float* __restrict__ in, unsigned int* __restrict__ out,
                        int npairs) {
    int i = blockIdx.x * blockDim.x + threadIdx.x;
    int stride = gridDim.x * blockDim.x;
    for (; i < npairs; i += stride) {
        float2 v = *(const float2*)(in + 2 * (size_t)i);
        out[i] = (unsigned int)f2bf(v.x) | ((unsigned int)f2bf(v.y) << 16);
    }
}

// ---------------------------------------------------------------------------
// deterministic bucket grouping (bucket = dst>>6), no global atomic returns
// ---------------------------------------------------------------------------
// per-chunk histogram over buckets, chunk-major: hist[c*NBUCK + b]
__global__ void hist_chunks(const void* ei, long long E, const int* flagp,
                            int* __restrict__ hist, int nbuck, long long CE) {
    __shared__ int lh[800];
    int use64 = flagp[0];
    int c = blockIdx.x, tid = threadIdx.x;
    for (int b = tid; b < nbuck; b += 256) lh[b] = 0;
    __syncthreads();
    long long beg = (long long)c * CE;
    long long end = beg + CE; if (end > E) end = E;
    for (long long e = beg + tid; e < end; e += 256) {
        int dst = edge_at(ei, E + e, use64);
        atomicAdd(&lh[dst >> 6], 1);
    }
    __syncthreads();
    for (int b = tid; b < nbuck; b += 256)
        hist[(size_t)c * nbuck + b] = lh[b];
}

// btot[b] = sum over chunks
__global__ void bucket_tot(const int* __restrict__ hist, int* __restrict__ btot,
                           int nbuck) {
    __shared__ int ws[4];
    int b = blockIdx.x, tid = threadIdx.x;
    int lane = tid & 63, wid = tid >> 6;
    int v = hist[(size_t)tid * nbuck + b];
#pragma unroll
    for (int off = 32; off >= 1; off >>= 1) v += __shfl_down(v, off, 64);
    if (lane == 0) ws[wid] = v;
    __syncthreads();
    if (tid == 0) btot[b] = ws[0] + ws[1] + ws[2] + ws[3];
}

// single block exclusive scan, in place; data[n] = total
__global__ void scan_excl(int* data, int n) {
    __shared__ int swsum[16];
    int tid = threadIdx.x;
    int lane = tid & 63, wid = tid >> 6;
    int carry = 0;
    for (int base = 0; base < n; base += 1024) {
        int i = base + tid;
        int v = (i < n) ? data[i] : 0;
        int sv = v;
#pragma unroll
        for (int off = 1; off < 64; off <<= 1) {
            int t = __shfl_up(sv, off, 64);
            if (lane >= off) sv += t;
        }
        __syncthreads();
        if (lane == 63) swsum[wid] = sv;
        __syncthreads();
        if (tid < 16) {
            int wv = swsum[tid];
#pragma unroll
            for (int off = 1; off < 16; off <<= 1) {
                int t = __shfl_up(wv, off, 16);
                if (tid >= off) wv += t;
            }
            swsum[tid] = wv;
        }
        __syncthreads();
        int woff = (wid > 0) ? swsum[wid - 1] : 0;
        int excl = carry + woff + sv - v;
        if (i < n) data[i] = excl;
        carry += swsum[15];
        __syncthreads();
    }
    if (tid == 0) data[n] = carry;
}

// per-bucket exclusive scan over the 256 chunks: pos[c*NBUCK+b]
__global__ void chunk_scan(const int* __restrict__ hist, const int* __restrict__ bstart,
                           int* __restrict__ pos, int nbuck) {
    __shared__ int wsum[4];
    int b = blockIdx.x, tid = threadIdx.x;
    int lane = tid & 63, wid = tid >> 6;
    int v = hist[(size_t)tid * nbuck + b];
    int sv = v;
#pragma unroll
    for (int off = 1; off < 64; off <<= 1) {
        int t = __shfl_up(sv, off, 64);
        if (lane >= off) sv += t;
    }
    if (lane == 63) wsum[wid] = sv;
    __syncthreads();
    int woff = 0;
    for (int w = 0; w < wid; ++w) woff += wsum[w];
    pos[(size_t)tid * nbuck + b] = bstart[b] + woff + sv - v;
}

// scatter edges into bucket-grouped order; packed = src | (local_dst<<16)
__global__ void scatter_grouped(const void* ei, long long E, const int* flagp,
                                const int* __restrict__ pos,
                                unsigned int* __restrict__ packed,
                                int nbuck, long long CE) {
    __shared__ int cur[800];
    int use64 = flagp[0];
    int c = blockIdx.x, tid = threadIdx.x;
    for (int b = tid; b < nbuck; b += 256) cur[b] = pos[(size_t)c * nbuck + b];
    __syncthreads();
    long long beg = (long long)c * CE;
    long long end = beg + CE; if (end > E) end = E;
    for (long long e = beg + tid; e < end; e += 256) {
        int dst = edge_at(ei, E + e, use64);
        int src = edge_at(ei, e, use64);
        int b = dst >> 6;
        int p = atomicAdd(&cur[b], 1);
        packed[p] = (unsigned int)src | ((unsigned int)(dst & 63) << 16);
    }
}

// per-bucket counting sort (64 bins) -> csr_src (ushort) + rowptr
__global__ void bucket_sort(const unsigned int* __restrict__ packed,
                            const int* __restrict__ bstart,
                            unsigned short* __restrict__ csr_src,
                            int* __restrict__ rowptr, int n, int nbuck) {
    __shared__ int bin[64];
    __shared__ int cur[64];
    int b = blockIdx.x, tid = threadIdx.x;
    int beg = bstart[b], end = bstart[b + 1];
    if (tid < 64) bin[tid] = 0;
    __syncthreads();
    for (int i = beg + tid; i < end; i += 256)
        atomicAdd(&bin[packed[i] >> 16], 1);
    __syncthreads();
    if (tid < 64) {
        int v = bin[tid];
        int sv = v;
#pragma unroll
        for (int off = 1; off < 64; off <<= 1) {
            int t = __shfl_up(sv, off, 64);
            if (tid >= off) sv += t;
        }
        int excl = sv - v;
        cur[tid] = beg + excl;
        int node = b * 64 + tid;
        if (node < n) rowptr[node] = beg + excl;
    }
    __syncthreads();
    for (int i = beg + tid; i < end; i += 256) {
        unsigned int p = packed[i];
        int q = atomicAdd(&cur[p >> 16], 1);
        csr_src[q] = (unsigned short)(p & 0xFFFFu);
    }
    if (b == nbuck - 1 && tid == 0) rowptr[n] = end;
}

// ---------------------------------------------------------------------------
// CSR aggregation from bf16 input (uint-packed pairs), fp32 accumulate.
// thread = (node, chunk of 8 values); 12 chunks cover D=96.
// ---------------------------------------------------------------------------
__global__ void aggregate(const unsigned int* __restrict__ in, float* __restrict__ out,
                          const int* __restrict__ rowptr,
                          const unsigned short* __restrict__ srcs,
                          int n, int normalize) {
    int t = blockIdx.x * blockDim.x + threadIdx.x;
    if (t >= n * 12) return;
    int node = t / 12, c = t % 12;
    int beg = rowptr[node], end = rowptr[node + 1];
    float acc[8];
#pragma unroll
    for (int j = 0; j < 8; ++j) acc[j] = 0.f;
    for (int i = beg; i < end; ++i) {
        int s = srcs[i];
        const uint4 v = *(const uint4*)(in + (size_t)s * 48 + c * 4);
        unsigned int u;
        u = v.x; acc[0] += __uint_as_float(u << 16); acc[1] += __uint_as_float(u & 0xffff0000u);
        u = v.y; acc[2] += __uint_as_float(u << 16); acc[3] += __uint_as_float(u & 0xffff0000u);
        u = v.z; acc[4] += __uint_as_float(u << 16); acc[5] += __uint_as_float(u & 0xffff0000u);
        u = v.w; acc[6] += __uint_as_float(u << 16); acc[7] += __uint_as_float(u & 0xffff0000u);
    }
    if (normalize) {
        float inv = 1.0f / fmaxf((float)(end - beg), 1.0f);
#pragma unroll
        for (int j = 0; j < 8; ++j) acc[j] *= inv;
    }
    float* o = out + (size_t)node * DN + c * 8;
    *(float4*)o = make_float4(acc[0], acc[1], acc[2], acc[3]);
    *(float4*)(o + 4) = make_float4(acc[4], acc[5], acc[6], acc[7]);
}

// ---------------------------------------------------------------------------
// out[n, j] = sum_k A[n,k] Wa[k,j] + sum_k B[n,k] Wb[k,j] + bias[j]
// wtrans=1: W is lin_w [j][192], chunk offset via pointer (+0 / +96)
// optional outb: bf16 copy of the output (for the next conv's gather)
// ---------------------------------------------------------------------------
__global__ __launch_bounds__(256) void gemm2(
        const float* __restrict__ inA, const float* __restrict__ inB,
        const float* __restrict__ Wa, const float* __restrict__ Wb,
        const float* __restrict__ bias, float* __restrict__ out,
        unsigned short* __restrict__ outb,
        int n, int wtrans, int dorelu) {
    __shared__ float As[DN][TILE + 4];
    __shared__ float Ws[DN][DN + 1];
    int tid = threadIdx.x;
    int row0 = blockIdx.x * TILE;
    int tc = tid & 15, tr = tid >> 4;

    float acc[4][6];
#pragma unroll
    for (int r = 0; r < 4; ++r)
#pragma unroll
        for (int c = 0; c < 6; ++c) acc[r][c] = 0.f;

    for (int ch = 0; ch < 2; ++ch) {
        const float* in = ch ? inB : inA;
        const float* W  = ch ? Wb  : Wa;
        if (!wtrans) {
            for (int i = tid; i < DN * 24; i += 256) {
                int k = i / 24, q = i % 24;
                const float4 v = *(const float4*)(W + (size_t)k * DN + q * 4);
                Ws[k][q * 4 + 0] = v.x; Ws[k][q * 4 + 1] = v.y;
                Ws[k][q * 4 + 2] = v.z; Ws[k][q * 4 + 3] = v.w;
            }
        } else {
            for (int i = tid; i < DN * 24; i += 256) {
                int j = i % DN, q = i / DN;
                const float4 v = *(const float4*)(W + (size_t)j * 192 + q * 4);
                Ws[q * 4 + 0][j] = v.x; Ws[q * 4 + 1][j] = v.y;
                Ws[q * 4 + 2][j] = v.z; Ws[q * 4 + 3][j] = v.w;
            }
        }
        for (int i = tid; i < TILE * 24; i += 256) {
            int q = i >> 6, r = i & 63;
            float4 v = make_float4(0.f, 0.f, 0.f, 0.f);
            if (row0 + r < n) v = *(const float4*)(in + (size_t)(row0 + r) * DN + q * 4);
            As[q * 4 + 0][r] = v.x; As[q * 4 + 1][r] = v.y;
            As[q * 4 + 2][r] = v.z; As[q * 4 + 3][r] = v.w;
        }
        __syncthreads();
#pragma unroll 4
        for (int k = 0; k < DN; ++k) {
            const float4 a = *(const float4*)&As[k][tr * 4];
            float w0 = Ws[k][tc +  0], w1 = Ws[k][tc + 16], w2 = Ws[k][tc + 32];
            float w3 = Ws[k][tc + 48], w4 = Ws[k][tc + 64], w5 = Ws[k][tc + 80];
            acc[0][0] += a.x * w0; acc[0][1] += a.x * w1; acc[0][2] += a.x * w2;
            acc[0][3] += a.x * w3; acc[0][4] += a.x * w4; acc[0][5] += a.x * w5;
            acc[1][0] += a.y * w0; acc[1][1] += a.y * w1; acc[1][2] += a.y * w2;
            acc[1][3] += a.y * w3; acc[1][4] += a.y * w4; acc[1][5] += a.y * w5;
            acc[2][0] += a.z * w0; acc[2][1] += a.z * w1; acc[2][2] += a.z * w2;
            acc[2][3] += a.z * w3; acc[2][4] += a.z * w4; acc[2][5] += a.z * w5;
            acc[3][0] += a.w * w0; acc[3][1] += a.w * w1; acc[3][2] += a.w * w2;
            acc[3][3] += a.w * w3; acc[3][4] += a.w * w4; acc[3][5] += a.w * w5;
        }
        __syncthreads();
    }

    float b[6];
#pragma unroll
    for (int c = 0; c < 6; ++c) b[c] = bias[tc + 16 * c];
#pragma unroll
    for (int rr = 0; rr < 4; ++rr) {
        int row = row0 + tr * 4 + rr;
        if (row < n) {
#pragma unroll
            for (int c = 0; c < 6; ++c) {
                float v = acc[rr][c] + b[c];
                if (dorelu) v = fmaxf(v, 0.f);
                out[(size_t)row * DN + tc + 16 * c] = v;
                if (outb) outb[(size_t)row * DN + tc + 16 * c] = f2bf(v);
            }
        }
    }
}

// ---------------------------------------------------------------------------
extern "C" void kernel_launch(void* const* d_in, const int* in_sizes, int n_in,
                              void* d_out, int out_size, void* d_ws, size_t ws_size,
                              hipStream_t stream) {
    const float* x   = (const float*)d_in[0];
    const void*  ei  = d_in[1];
    const float* W1r = (const float*)d_in[2];
    const float* W1n = (const float*)d_in[3];
    const float* b1  = (const float*)d_in[4];
    const float* W2r = (const float*)d_in[5];
    const float* W2n = (const float*)d_in[6];
    const float* b2  = (const float*)d_in[7];
    const float* lw  = (const float*)d_in[8];
    const float* lb  = (const float*)d_in[9];
    float* out = (float*)d_out;

    const int N = in_sizes[0] / DN;         // 50000
    const long long E = in_sizes[1] / 2;    // 800000
    const int NBUCK = (N + 63) / 64;        // 782
    const long long CE = (E + NCHUNK - 1) / NCHUNK;
    const size_t ND = (size_t)N * DN;

    float* agg = (float*)d_ws;                       // [N*96]
    float* h1  = agg + ND;                           // [N*96]
    float* h2  = h1 + ND;                            // [N*96], aliases xb+h1b
    unsigned int* xb  = (unsigned int*)h2;           // [N*48] bf16 pairs
    unsigned int* h1b = xb + ND / 2;                 // [N*48]
    int* hist   = (int*)(h2 + ND);                   // [NCHUNK*NBUCK]
    int* pos    = hist + NCHUNK * NBUCK;             // [NCHUNK*NBUCK]
    int* btot   = pos + NCHUNK * NBUCK;              // [NBUCK+1] -> bstart
    int* rowptr = btot + NBUCK + 1;                  // [N+1]
    unsigned int* packed = (unsigned int*)(rowptr + N + 1);  // [E]
    unsigned short* csr_src = (unsigned short*)(packed + E); // [E]
    int* flagp  = (int*)(csr_src + E) + 1;           // 1

    detect_i64<<<1, 256, 0, stream>>>((const unsigned int*)ei, flagp);
    to_bf16<<<2048, 256, 0, stream>>>(x, xb, (int)(ND / 2));

    // build bucket-grouped CSR (deterministic, no global atomic returns)
    hist_chunks<<<NCHUNK, 256, 0, stream>>>(ei, E, flagp, hist, NBUCK, CE);
    bucket_tot<<<NBUCK, 256, 0, stream>>>(hist, btot, NBUCK);
    scan_excl<<<1, 1024, 0, stream>>>(btot, NBUCK);
    chunk_scan<<<NBUCK, 256, 0, stream>>>(hist, btot, pos, NBUCK);
    scatter_grouped<<<NCHUNK, 256, 0, stream>>>(ei, E, flagp, pos, packed, NBUCK, CE);
    bucket_sort<<<NBUCK, 256, 0, stream>>>(packed, btot, csr_src, rowptr, N, NBUCK);

    int ab = (N * 12 + 255) / 256;
    int gb = (N + TILE - 1) / TILE;

    // conv1: h1 = x@W1r + agg(x)@W1n + b1   (also emit h1 in bf16)
    aggregate<<<ab, 256, 0, stream>>>(xb, agg, rowptr, csr_src, N, 0);
    gemm2<<<gb, 256, 0, stream>>>(x, agg, W1r, W1n, b1, h1, (unsigned short*)h1b, N, 0, 0);
    // conv2: h2 = h1@W2r + (agg(h1)/deg)@W2n + b2   (h2 overwrites xb/h1b)
    aggregate<<<ab, 256, 0, stream>>>(h1b, agg, rowptr, csr_src, N, 1);
    gemm2<<<gb, 256, 0, stream>>>(h1, agg, W2r, W2n, b2, h2, (unsigned short*)0, N, 0, 0);
    // out = relu([h1|h2] @ lin_w.T + lin_b)
    gemm2<<<gb, 256, 0, stream>>>(h1, h2, lw, lw + DN, lb, out, (unsigned short*)0, N, 1, 1);
}

// Round 3
// 167.498 us; speedup vs baseline: 2.2744x; 1.5055x over previous
//
#include <hip/hip_runtime.h>

#define DN 96
#define TILE 64
#define NCHUNK 256

typedef __attribute__((ext_vector_type(8))) short bf16x8;
typedef __attribute__((ext_vector_type(4))) float f32x4;

// ---------------------------------------------------------------------------
// helpers
// ---------------------------------------------------------------------------
__device__ __forceinline__ int edge_at(const void* ei, long long idx, int use64) {
    if (use64) return (int)((const long long*)ei)[idx];
    return ((const int*)ei)[idx];
}

__device__ __forceinline__ unsigned short f2bf(float f) {
    unsigned int u = __float_as_uint(f);
    return (unsigned short)((u + 0x7fffu + ((u >> 16) & 1u)) >> 16);  // RNE
}

__global__ void detect_i64(const unsigned int* w, int* flagp) {
    __shared__ int ok;
    if (threadIdx.x == 0) ok = 1;
    __syncthreads();
    for (int i = threadIdx.x; i < 1024; i += blockDim.x)
        if (w[2 * i + 1] != 0u) ok = 0;
    __syncthreads();
    if (threadIdx.x == 0) flagp[0] = ok;
}

// x (fp32) -> packed bf16 pairs (uint): low ushort = even elem
__global__ void to_bf16(const float* __restrict__ in, unsigned int* __restrict__ out,
                        int npairs) {
    int i = blockIdx.x * blockDim.x + threadIdx.x;
    int stride = gridDim.x * blockDim.x;
    for (; i < npairs; i += stride) {
        float2 v = *(const float2*)(in + 2 * (size_t)i);
        out[i] = (unsigned int)f2bf(v.x) | ((unsigned int)f2bf(v.y) << 16);
    }
}

// WT[j][k] (bf16, [96][192]) = k<96 ? Wa[k][j] : Wb[k-96][j]
__global__ void build_wt_conv(const float* __restrict__ Wa, const float* __restrict__ Wb,
                              unsigned short* __restrict__ WT) {
    int i = blockIdx.x * 256 + threadIdx.x;
    if (i >= DN * 192) return;
    int j = i / 192, k = i % 192;
    float v = (k < DN) ? Wa[(size_t)k * DN + j] : Wb[(size_t)(k - DN) * DN + j];
    WT[i] = f2bf(v);
}

// WT[j][k] = lin_w[j][k]  (lin_w is [96][192] row-major)
__global__ void build_wt_lin(const float* __restrict__ lw, unsigned short* __restrict__ WT) {
    int i = blockIdx.x * 256 + threadIdx.x;
    if (i >= DN * 192) return;
    WT[i] = f2bf(lw[i]);
}

// ---------------------------------------------------------------------------
// deterministic bucket grouping (bucket = dst>>6), no global atomic returns
// ---------------------------------------------------------------------------
__global__ void hist_chunks(const void* ei, long long E, const int* flagp,
                            int* __restrict__ hist, int nbuck, long long CE) {
    __shared__ int lh[800];
    int use64 = flagp[0];
    int c = blockIdx.x, tid = threadIdx.x;
    for (int b = tid; b < nbuck; b += 256) lh[b] = 0;
    __syncthreads();
    long long beg = (long long)c * CE;
    long long end = beg + CE; if (end > E) end = E;
    for (long long e = beg + tid; e < end; e += 256) {
        int dst = edge_at(ei, E + e, use64);
        atomicAdd(&lh[dst >> 6], 1);
    }
    __syncthreads();
    for (int b = tid; b < nbuck; b += 256)
        hist[(size_t)c * nbuck + b] = lh[b];
}

__global__ void bucket_tot(const int* __restrict__ hist, int* __restrict__ btot,
                           int nbuck) {
    __shared__ int ws[4];
    int b = blockIdx.x, tid = threadIdx.x;
    int lane = tid & 63, wid = tid >> 6;
    int v = hist[(size_t)tid * nbuck + b];
#pragma unroll
    for (int off = 32; off >= 1; off >>= 1) v += __shfl_down(v, off, 64);
    if (lane == 0) ws[wid] = v;
    __syncthreads();
    if (tid == 0) btot[b] = ws[0] + ws[1] + ws[2] + ws[3];
}

__global__ void scan_excl(int* data, int n) {
    __shared__ int swsum[16];
    int tid = threadIdx.x;
    int lane = tid & 63, wid = tid >> 6;
    int carry = 0;
    for (int base = 0; base < n; base += 1024) {
        int i = base + tid;
        int v = (i < n) ? data[i] : 0;
        int sv = v;
#pragma unroll
        for (int off = 1; off < 64; off <<= 1) {
            int t = __shfl_up(sv, off, 64);
            if (lane >= off) sv += t;
        }
        __syncthreads();
        if (lane == 63) swsum[wid] = sv;
        __syncthreads();
        if (tid < 16) {
            int wv = swsum[tid];
#pragma unroll
            for (int off = 1; off < 16; off <<= 1) {
                int t = __shfl_up(wv, off, 16);
                if (tid >= off) wv += t;
            }
            swsum[tid] = wv;
        }
        __syncthreads();
        int woff = (wid > 0) ? swsum[wid - 1] : 0;
        int excl = carry + woff + sv - v;
        if (i < n) data[i] = excl;
        carry += swsum[15];
        __syncthreads();
    }
    if (tid == 0) data[n] = carry;
}

__global__ void chunk_scan(const int* __restrict__ hist, const int* __restrict__ bstart,
                           int* __restrict__ pos, int nbuck) {
    __shared__ int wsum[4];
    int b = blockIdx.x, tid = threadIdx.x;
    int lane = tid & 63, wid = tid >> 6;
    int v = hist[(size_t)tid * nbuck + b];
    int sv = v;
#pragma unroll
    for (int off = 1; off < 64; off <<= 1) {
        int t = __shfl_up(sv, off, 64);
        if (lane >= off) sv += t;
    }
    if (lane == 63) wsum[wid] = sv;
    __syncthreads();
    int woff = 0;
    for (int w = 0; w < wid; ++w) woff += wsum[w];
    pos[(size_t)tid * nbuck + b] = bstart[b] + woff + sv - v;
}

__global__ void scatter_grouped(const void* ei, long long E, const int* flagp,
                                const int* __restrict__ pos,
                                unsigned int* __restrict__ packed,
                                int nbuck, long long CE) {
    __shared__ int cur[800];
    int use64 = flagp[0];
    int c = blockIdx.x, tid = threadIdx.x;
    for (int b = tid; b < nbuck; b += 256) cur[b] = pos[(size_t)c * nbuck + b];
    __syncthreads();
    long long beg = (long long)c * CE;
    long long end = beg + CE; if (end > E) end = E;
    for (long long e = beg + tid; e < end; e += 256) {
        int dst = edge_at(ei, E + e, use64);
        int src = edge_at(ei, e, use64);
        int b = dst >> 6;
        int p = atomicAdd(&cur[b], 1);
        packed[p] = (unsigned int)src | ((unsigned int)(dst & 63) << 16);
    }
}

__global__ void bucket_sort(const unsigned int* __restrict__ packed,
                            const int* __restrict__ bstart,
                            unsigned short* __restrict__ csr_src,
                            int* __restrict__ rowptr, int n, int nbuck) {
    __shared__ int bin[64];
    __shared__ int cur[64];
    int b = blockIdx.x, tid = threadIdx.x;
    int beg = bstart[b], end = bstart[b + 1];
    if (tid < 64) bin[tid] = 0;
    __syncthreads();
    for (int i = beg + tid; i < end; i += 256)
        atomicAdd(&bin[packed[i] >> 16], 1);
    __syncthreads();
    if (tid < 64) {
        int v = bin[tid];
        int sv = v;
#pragma unroll
        for (int off = 1; off < 64; off <<= 1) {
            int t = __shfl_up(sv, off, 64);
            if (tid >= off) sv += t;
        }
        int excl = sv - v;
        cur[tid] = beg + excl;
        int node = b * 64 + tid;
        if (node < n) rowptr[node] = beg + excl;
    }
    __syncthreads();
    for (int i = beg + tid; i < end; i += 256) {
        unsigned int p = packed[i];
        int q = atomicAdd(&cur[p >> 16], 1);
        csr_src[q] = (unsigned short)(p & 0xFFFFu);
    }
    if (b == nbuck - 1 && tid == 0) rowptr[n] = end;
}

// ---------------------------------------------------------------------------
// CSR aggregation: bf16 in (packed uints), fp32 accumulate, bf16 packed out.
// thread = (node, chunk of 8 values); 12 chunks cover D=96.
// ---------------------------------------------------------------------------
__global__ void aggregate(const unsigned int* __restrict__ in, unsigned int* __restrict__ out,
                          const int* __restrict__ rowptr,
                          const unsigned short* __restrict__ srcs,
                          int n, int normalize) {
    int t = blockIdx.x * blockDim.x + threadIdx.x;
    if (t >= n * 12) return;
    int node = t / 12, c = t % 12;
    int beg = rowptr[node], end = rowptr[node + 1];
    float acc[8];
#pragma unroll
    for (int j = 0; j < 8; ++j) acc[j] = 0.f;
    for (int i = beg; i < end; ++i) {
        int s = srcs[i];
        const uint4 v = *(const uint4*)(in + (size_t)s * 48 + c * 4);
        unsigned int u;
        u = v.x; acc[0] += __uint_as_float(u << 16); acc[1] += __uint_as_float(u & 0xffff0000u);
        u = v.y; acc[2] += __uint_as_float(u << 16); acc[3] += __uint_as_float(u & 0xffff0000u);
        u = v.z; acc[4] += __uint_as_float(u << 16); acc[5] += __uint_as_float(u & 0xffff0000u);
        u = v.w; acc[6] += __uint_as_float(u << 16); acc[7] += __uint_as_float(u & 0xffff0000u);
    }
    if (normalize) {
        float inv = 1.0f / fmaxf((float)(end - beg), 1.0f);
#pragma unroll
        for (int j = 0; j < 8; ++j) acc[j] *= inv;
    }
    uint4 r;
    r.x = (unsigned int)f2bf(acc[0]) | ((unsigned int)f2bf(acc[1]) << 16);
    r.y = (unsigned int)f2bf(acc[2]) | ((unsigned int)f2bf(acc[3]) << 16);
    r.z = (unsigned int)f2bf(acc[4]) | ((unsigned int)f2bf(acc[5]) << 16);
    r.w = (unsigned int)f2bf(acc[6]) | ((unsigned int)f2bf(acc[7]) << 16);
    *(uint4*)(out + (size_t)node * 48 + c * 4) = r;
}

// ---------------------------------------------------------------------------
// MFMA GEMM: out[n,j] = [A|B][n,k] @ WT[j,k]^T + bias[j]   (K = 192)
// A,B bf16 [n][96]; WT bf16 [96][192] (j-major). Block: 4 waves x 32 rows.
// A-frags read direct from global; WT staged in LDS padded to stride 200.
// Symmetric (lane,elem)->k mapping on A and B cancels any HW k-permutation.
// ---------------------------------------------------------------------------
__global__ __launch_bounds__(256) void gemm_mfma(
        const unsigned short* __restrict__ Abf, const unsigned short* __restrict__ Bbf,
        const unsigned short* __restrict__ WT, const float* __restrict__ bias,
        float* __restrict__ outf, unsigned short* __restrict__ outb,
        int n, int dorelu) {
    __shared__ unsigned int WTl[DN * 100];   // [96][100] uints (k-pairs, padded)
    int tid = threadIdx.x;
    const unsigned int* WTg = (const unsigned int*)WT;   // [96][96] uints
    for (int i = tid; i < DN * 96; i += 256) {
        int j = i / 96, m = i - j * 96;
        WTl[j * 100 + m] = WTg[i];
    }
    __syncthreads();

    int wid = tid >> 6, lane = tid & 63;
    int lg = lane >> 4, lr = lane & 15;
    int rowbase = blockIdx.x * 128 + wid * 32;

    f32x4 acc[2][6];
#pragma unroll
    for (int rt = 0; rt < 2; ++rt)
#pragma unroll
        for (int ct = 0; ct < 6; ++ct) acc[rt][ct] = (f32x4){0.f, 0.f, 0.f, 0.f};

    const unsigned short* WTs = (const unsigned short*)WTl;
#pragma unroll
    for (int kt = 0; kt < 6; ++kt) {
        const unsigned short* src = (kt < 3) ? Abf : Bbf;
        int kk = (kt < 3 ? kt : kt - 3) * 32 + lg * 8;
        bf16x8 afrag[2];
#pragma unroll
        for (int rt = 0; rt < 2; ++rt) {
            int row = rowbase + rt * 16 + lr;
            if (row >= n) row = n - 1;
            afrag[rt] = *(const bf16x8*)(src + (size_t)row * DN + kk);
        }
        int koff = kt * 32 + lg * 8;
#pragma unroll
        for (int ct = 0; ct < 6; ++ct) {
            bf16x8 bfrag = *(const bf16x8*)(WTs + (ct * 16 + lr) * 200 + koff);
            acc[0][ct] = __builtin_amdgcn_mfma_f32_16x16x32_bf16(afrag[0], bfrag, acc[0][ct], 0, 0, 0);
            acc[1][ct] = __builtin_amdgcn_mfma_f32_16x16x32_bf16(afrag[1], bfrag, acc[1][ct], 0, 0, 0);
        }
    }

#pragma unroll
    for (int ct = 0; ct < 6; ++ct) {
        int col = ct * 16 + lr;
        float bv = bias[col];
#pragma unroll
        for (int rt = 0; rt < 2; ++rt)
#pragma unroll
            for (int r = 0; r < 4; ++r) {
                int row = rowbase + rt * 16 + lg * 4 + r;
                if (row < n) {
                    float v = acc[rt][ct][r] + bv;
                    if (dorelu) v = fmaxf(v, 0.f);
                    if (outf) outf[(size_t)row * DN + col] = v;
                    if (outb) outb[(size_t)row * DN + col] = f2bf(v);
                }
            }
    }
}

// ---------------------------------------------------------------------------
extern "C" void kernel_launch(void* const* d_in, const int* in_sizes, int n_in,
                              void* d_out, int out_size, void* d_ws, size_t ws_size,
                              hipStream_t stream) {
    const float* x   = (const float*)d_in[0];
    const void*  ei  = d_in[1];
    const float* W1r = (const float*)d_in[2];
    const float* W1n = (const float*)d_in[3];
    const float* b1  = (const float*)d_in[4];
    const float* W2r = (const float*)d_in[5];
    const float* W2n = (const float*)d_in[6];
    const float* b2  = (const float*)d_in[7];
    const float* lw  = (const float*)d_in[8];
    const float* lb  = (const float*)d_in[9];
    float* out = (float*)d_out;

    const int N = in_sizes[0] / DN;         // 50000
    const long long E = in_sizes[1] / 2;    // 800000
    const int NBUCK = (N + 63) / 64;        // 782
    const long long CE = (E + NCHUNK - 1) / NCHUNK;
    const size_t NP = (size_t)N * 48;       // bf16-pair uints per feature map

    unsigned int* xb   = (unsigned int*)d_ws;        // [N*48]
    unsigned int* h1b  = xb + NP;                    // [N*48]
    unsigned int* h2b  = h1b + NP;                   // [N*48]
    unsigned int* aggb = h2b + NP;                   // [N*48]
    unsigned short* WT1 = (unsigned short*)(aggb + NP);   // [96*192]
    unsigned short* WT2 = WT1 + DN * 192;
    unsigned short* WT3 = WT2 + DN * 192;
    int* hist   = (int*)(WT3 + DN * 192);            // [NCHUNK*NBUCK]
    int* pos    = hist + NCHUNK * NBUCK;             // [NCHUNK*NBUCK]
    int* btot   = pos + NCHUNK * NBUCK;              // [NBUCK+1]
    int* rowptr = btot + NBUCK + 1;                  // [N+1]
    unsigned int* packed = (unsigned int*)(rowptr + N + 1);  // [E]
    unsigned short* csr_src = (unsigned short*)(packed + E); // [E]
    int* flagp  = (int*)(csr_src + E);               // 1

    detect_i64<<<1, 256, 0, stream>>>((const unsigned int*)ei, flagp);
    to_bf16<<<2048, 256, 0, stream>>>(x, xb, (int)NP);
    int wb = (DN * 192 + 255) / 256;
    build_wt_conv<<<wb, 256, 0, stream>>>(W1r, W1n, WT1);
    build_wt_conv<<<wb, 256, 0, stream>>>(W2r, W2n, WT2);
    build_wt_lin<<<wb, 256, 0, stream>>>(lw, WT3);

    hist_chunks<<<NCHUNK, 256, 0, stream>>>(ei, E, flagp, hist, NBUCK, CE);
    bucket_tot<<<NBUCK, 256, 0, stream>>>(hist, btot, NBUCK);
    scan_excl<<<1, 1024, 0, stream>>>(btot, NBUCK);
    chunk_scan<<<NBUCK, 256, 0, stream>>>(hist, btot, pos, NBUCK);
    scatter_grouped<<<NCHUNK, 256, 0, stream>>>(ei, E, flagp, pos, packed, NBUCK, CE);
    bucket_sort<<<NBUCK, 256, 0, stream>>>(packed, btot, csr_src, rowptr, N, NBUCK);

    int ab = (N * 12 + 255) / 256;
    int gb = (N + 127) / 128;

    // conv1: h1 = x@W1r + agg(x)@W1n + b1  (bf16 out only)
    aggregate<<<ab, 256, 0, stream>>>(xb, aggb, rowptr, csr_src, N, 0);
    gemm_mfma<<<gb, 256, 0, stream>>>((const unsigned short*)xb, (const unsigned short*)aggb,
                                      WT1, b1, (float*)0, (unsigned short*)h1b, N, 0);
    // conv2: h2 = h1@W2r + (agg(h1)/deg)@W2n + b2  (bf16 out only)
    aggregate<<<ab, 256, 0, stream>>>(h1b, aggb, rowptr, csr_src, N, 1);
    gemm_mfma<<<gb, 256, 0, stream>>>((const unsigned short*)h1b, (const unsigned short*)aggb,
                                      WT2, b2, (float*)0, (unsigned short*)h2b, N, 0);
    // out = relu([h1|h2] @ lin_w.T + lin_b)  (fp32 out)
    gemm_mfma<<<gb, 256, 0, stream>>>((const unsigned short*)h1b, (const unsigned short*)h2b,
                                      WT3, lb, out, (unsigned short*)0, N, 1);
}